// Round 6
// baseline (174.787 us; speedup 1.0000x reference)
//
#include <hip/hip_runtime.h>
#include <hip/hip_bf16.h>
#include <stdint.h>

#define IN_F 4096
#define OUT_F 11008
#define NUM_CH 128
#define NUM_NORM 3968
#define BATCH 64
#define KSPLIT 8
#define KCHUNK (IN_F / KSPLIT)   // 512
#define NMEGA (KCHUNK / 128)     // 4 megasteps of K=128
#define BS 136                   // k-stride of a wave tile in shorts (0-conflict family, 16B-aligned)

typedef short short8 __attribute__((ext_vector_type(8)));
typedef float float4v __attribute__((ext_vector_type(4)));
typedef int int4v __attribute__((ext_vector_type(4)));

__device__ __forceinline__ unsigned short f2bf(float f) {
    union { float f; unsigned u; } v; v.f = f;
    unsigned u = v.u;
    return (unsigned short)((u + 0x7FFFu + ((u >> 16) & 1u)) >> 16);
}

__device__ __forceinline__ unsigned pk_bf16(float lo, float hi) {
    __hip_bfloat162 h = __float22bfloat162_rn(make_float2(lo, hi));  // v_cvt_pk_bf16_f32
    union { __hip_bfloat162 h; unsigned u; } c; c.h = h; return c.u;
}

// out[m][n] = bias[n]  (pre-init so qgemm can atomicAdd partials)
__global__ __launch_bounds__(256) void init_out(
        const float* __restrict__ bias, float* __restrict__ out) {
    const int i = blockIdx.x * 256 + threadIdx.x;        // float4 index
    const int c = i % (OUT_F / 4);
    const float4v b4 = *reinterpret_cast<const float4v*>(bias + c * 4);
    reinterpret_cast<float4v*>(out)[i] = b4;
}

// Gather-permute x into bf16 xp[64][4096]:
//   pos j in [0,3968): x[:, normal_idx[j]]   pos 3968+c: x[:, cherry_indices[c]]
__global__ __launch_bounds__(256) void permute_x(
        const float* __restrict__ x, const int* __restrict__ cidx,
        unsigned short* __restrict__ xp) {
    int i = blockIdx.x * blockDim.x + threadIdx.x;
    int b = blockIdx.y;
    int lo = 0, hi = NUM_CH;
    while (lo < hi) { int mid = (lo + hi) >> 1; if (cidx[mid] < i) lo = mid + 1; else hi = mid; }
    bool isch = (lo < NUM_CH) && (cidx[lo] == i);
    int pos = isch ? (NUM_NORM + lo) : (i - lo);
    xp[b * IN_F + pos] = f2bf(x[b * IN_F + i]);
}

// BARRIER-FREE fused dequant + bf16 MFMA GEMM.
// Each wave owns a private 32-n stripe and a private LDS tile (32 x 128k).
// No __syncthreads anywhere -> no vmcnt(0) drain; prefetched loads stay in
// flight across megastep boundaries. Same-wave DS ordering is in-order HW.
// Register blocking: 4 m-frags x 2 n-frags, 8 MFMAs per 32-k substep.
__global__ __launch_bounds__(256, 3) void qgemm(
        const unsigned short* __restrict__ xp, const int* __restrict__ qw,
        const float* __restrict__ cw, const float* __restrict__ scales,
        float* __restrict__ out) {
    __shared__ unsigned short Bt[4][32][BS];   // 4 wave-private tiles, 34.8 KB total

    const int tid  = threadIdx.x;
    const int wave = tid >> 6;
    const int lane = tid & 63;
    const int ln   = lane & 15;      // fragment index
    const int lq   = lane >> 4;      // k-quad
    const int c4   = (lane & 7) * 4; // staging col group (4 cols)
    const int rg   = lane >> 3;      // staging row group 0..7

    const int n0w   = (blockIdx.x * 4 + wave) * 32;   // wave's n stripe
    const int kbase = blockIdx.y * KCHUNK;

    unsigned short (*tile)[BS] = Bt[wave];

    const int*   qcolp = qw + n0w + c4;
    const float* scolp = scales + n0w + c4;
    const float* ccolp = cw + n0w + c4;

    float4v acc[4][2];   // [mt][nf]
    #pragma unroll
    for (int mt = 0; mt < 4; ++mt)
        #pragma unroll
        for (int nf = 0; nf < 2; ++nf) acc[mt][nf] = (float4v){0.f, 0.f, 0.f, 0.f};

    // ---- prologue: issue megastep-0 qweight loads (kbase is always normal) ----
    int4v qcur[8]; float4v scur;
    {
        const size_t rb = (size_t)(kbase >> 1) + rg * 8;
        #pragma unroll
        for (int i = 0; i < 8; ++i)
            qcur[i] = *reinterpret_cast<const int4v*>(qcolp + (rb + i) * OUT_F);
        scur = *reinterpret_cast<const float4v*>(scolp + (size_t)(kbase >> 7) * OUT_F);
    }

    for (int s = 0; s < NMEGA; ++s) {
        const int k0 = kbase + s * 128;

        if (k0 < NUM_NORM) {
            int4v q[8]; const float4v sc = scur;
            #pragma unroll
            for (int i = 0; i < 8; ++i) q[i] = qcur[i];
            // prefetch next megastep's qweight a full megastep ahead (no
            // barrier will drain it)
            const int kn = k0 + 128;
            if (s + 1 < NMEGA && kn < NUM_NORM) {
                const size_t rb = (size_t)(kn >> 1) + rg * 8;
                #pragma unroll
                for (int i = 0; i < 8; ++i)
                    qcur[i] = *reinterpret_cast<const int4v*>(qcolp + (rb + i) * OUT_F);
                scur = *reinterpret_cast<const float4v*>(scolp + (size_t)(kn >> 7) * OUT_F);
            }
            // dequant: lane covers rows rg*8..+7 (k = rg*16..+15), cols c4..c4+3
            #pragma unroll
            for (int j = 0; j < 4; ++j) {
                const float s1 = sc[j];
                #pragma unroll
                for (int p = 0; p < 2; ++p) {
                    union { short8 v; unsigned u[4]; } wv;
                    #pragma unroll
                    for (int m = 0; m < 4; ++m) {
                        const int qq = q[p * 4 + m][j];
                        wv.u[m] = pk_bf16((float)((qq & 0xF) - 8) * s1,
                                          (float)(((qq >> 4) & 0xF) - 8) * s1);
                    }
                    *reinterpret_cast<short8*>(&tile[c4 + j][rg * 16 + p * 8]) = wv.v;
                }
            }
        } else {
            // pure-cherry megastep (k0 == NUM_NORM; only ky==7, s==3)
            float4v chv[16];
            #pragma unroll
            for (int t = 0; t < 16; ++t)
                chv[t] = *reinterpret_cast<const float4v*>(
                    ccolp + (size_t)(rg * 16 + t) * OUT_F);
            #pragma unroll
            for (int j = 0; j < 4; ++j) {
                #pragma unroll
                for (int p = 0; p < 2; ++p) {
                    union { short8 v; unsigned u[4]; } wv;
                    #pragma unroll
                    for (int m = 0; m < 4; ++m)
                        wv.u[m] = pk_bf16(chv[p * 8 + 2 * m][j], chv[p * 8 + 2 * m + 1][j]);
                    *reinterpret_cast<short8*>(&tile[c4 + j][rg * 16 + p * 8]) = wv.v;
                }
            }
        }

        // ---- MFMA phase: wave-private tile, NO barrier ----
        short8 a_sub[4];
        #pragma unroll
        for (int mt = 0; mt < 4; ++mt)
            a_sub[mt] = *reinterpret_cast<const short8*>(
                xp + (size_t)(mt * 16 + ln) * IN_F + k0 + (lq << 3));

        #pragma unroll
        for (int sub = 0; sub < 4; ++sub) {
            const short8 b0 = *reinterpret_cast<const short8*>(
                &tile[ln][sub * 32 + (lq << 3)]);
            const short8 b1 = *reinterpret_cast<const short8*>(
                &tile[16 + ln][sub * 32 + (lq << 3)]);
            short8 a_nxt[4];
            if (sub < 3) {
                #pragma unroll
                for (int mt = 0; mt < 4; ++mt)
                    a_nxt[mt] = *reinterpret_cast<const short8*>(
                        xp + (size_t)(mt * 16 + ln) * IN_F + k0 + (sub + 1) * 32 + (lq << 3));
            }
            #pragma unroll
            for (int mt = 0; mt < 4; ++mt) {
                acc[mt][0] = __builtin_amdgcn_mfma_f32_16x16x32_bf16(a_sub[mt], b0, acc[mt][0], 0, 0, 0);
                acc[mt][1] = __builtin_amdgcn_mfma_f32_16x16x32_bf16(a_sub[mt], b1, acc[mt][1], 0, 0, 0);
            }
            if (sub < 3) {
                #pragma unroll
                for (int mt = 0; mt < 4; ++mt) a_sub[mt] = a_nxt[mt];
            }
        }
    }

    // Epilogue: D col = ln -> n, row = lq*4 + r -> m within mt; atomic partials
    #pragma unroll
    for (int mt = 0; mt < 4; ++mt) {
        #pragma unroll
        for (int nf = 0; nf < 2; ++nf) {
            const int n = n0w + nf * 16 + ln;
            #pragma unroll
            for (int r = 0; r < 4; ++r) {
                const int m = mt * 16 + (lq << 2) + r;
                atomicAdd(&out[(size_t)m * OUT_F + n], acc[mt][nf][r]);
            }
        }
    }
}

extern "C" void kernel_launch(void* const* d_in, const int* in_sizes, int n_in,
                              void* d_out, int out_size, void* d_ws, size_t ws_size,
                              hipStream_t stream) {
    const float* x      = (const float*)d_in[0];
    const int*   qw     = (const int*)d_in[1];     // uint8 widened to int32 by harness
    const float* cw     = (const float*)d_in[2];
    const int*   cidx   = (const int*)d_in[3];
    const float* scales = (const float*)d_in[4];
    const float* bias   = (const float*)d_in[5];
    float*       out    = (float*)d_out;
    unsigned short* xp  = (unsigned short*)d_ws;   // 64*4096 bf16 = 512 KB

    init_out<<<(BATCH * OUT_F / 4) / 256, 256, 0, stream>>>(bias, out);
    dim3 pgrid(IN_F / 256, BATCH);
    permute_x<<<pgrid, 256, 0, stream>>>(x, cidx, xp);
    qgemm<<<dim3(OUT_F / 128, KSPLIT), 256, 0, stream>>>(xp, qw, cw, scales, out);
}